// Round 16
// baseline (428.162 us; speedup 1.0000x reference)
//
#include <hip/hip_runtime.h>
#include <math.h>
#include <stdint.h>

typedef unsigned int u32;
typedef unsigned short u16;
typedef __bf16 bf16x8 __attribute__((ext_vector_type(8)));
typedef float f32x4 __attribute__((ext_vector_type(4)));
typedef unsigned short u16x8 __attribute__((ext_vector_type(8)));
typedef unsigned short u16x4 __attribute__((ext_vector_type(4)));

constexpr int   Bb  = 2;
constexpr int   Ss  = 1024;
constexpr int   HID = 4096;
constexpr int   NH  = 32;
constexpr int   NKV = 8;
constexpr int   HD  = 128;
constexpr float SCALING = 0.0883883476483184405501f; // 128^-0.5

enum { M_QKV = 0, M_OUT = 3 };

// fp32 -> bf16 RTNE (bit trick; finite values only here)
__device__ __forceinline__ u16 f2bf(float f) {
  u32 u = __builtin_bit_cast(u32, f);
  u = u + 0x7fffu + ((u >> 16) & 1u);
  return (u16)(u >> 16);
}

// async global->LDS, 16B per lane (offset arg always 0 — verified semantics)
__device__ __forceinline__ void gld_lds16(const void* g, void* l) {
  __builtin_amdgcn_global_load_lds(
      (const __attribute__((address_space(1))) u32*)(uintptr_t)g,
      (__attribute__((address_space(3))) u32*)(uintptr_t)l, 16, 0, 0);
}

// ---------------------------------------------------------------------------
// bf16 MFMA GEMM, m201-style phase-interleaved schedule:
//   BM=256, BN=128, BK=64, 512 threads = 8 waves stacked on M (wave tile
//   32M x 128N -> each wave owns a FULL head: RoPE epilogue maps in-register).
//   3 LDS buffers (144 KB), stage distance 2 K-tiles, counted vmcnt(6).
//   4 phases per K-tile, each {ds_read subtile | issue 2 gld_lds -> barrier ->
//   lgkmcnt(0) -> setprio(1) -> 8 MFMA -> setprio(0) -> barrier}.
//   Swizzle: 16B slot ^ (row&7) on 128 B rows (<=2-way, free).
// ---------------------------------------------------------------------------
template <int MODE, int K>
__global__ __launch_bounds__(512, 1) void mfma_gemm(
    const u16* __restrict__ Abf_g,
    const u16* __restrict__ B0, const u16* __restrict__ B1,
    const u16* __restrict__ B2,
    u16* __restrict__ Cq, float* __restrict__ Ckf, float* __restrict__ Cv,
    float* __restrict__ Cfo,
    const float* __restrict__ cosp, const float* __restrict__ sinp) {
  __shared__ u16 As[3][256 * 64];  // 3 x 32 KB
  __shared__ u16 Bs[3][128 * 64];  // 3 x 16 KB

  const int tid = threadIdx.x;
  const int lane = tid & 63;
  const int wid = tid >> 6;        // 0..7 (M-stacked waves)
  const int fr = lane & 15;
  const int fq = lane >> 4;

  const int bx = blockIdx.x;
  const int m0 = blockIdx.y * 256;

  const u16* Abf = Abf_g + (size_t)m0 * K;
  const u16* Bp = nullptr;
  int which = 0;

  if (MODE == M_QKV) {
    if (bx < 32)      { which = 0; Bp = B0 + (size_t)bx * 128 * K; }
    else if (bx < 40) { which = 1; Bp = B1 + (size_t)(bx - 32) * 128 * K; }
    else              { which = 2; Bp = B2 + (size_t)(bx - 40) * 128 * K; }
  } else {  // M_OUT
    Bp = B0 + (size_t)bx * 128 * K;
  }

  f32x4 acc[2][8];
#pragma unroll
  for (int i = 0; i < 2; i++)
#pragma unroll
    for (int j = 0; j < 8; j++) acc[i][j] = (f32x4){0.f, 0.f, 0.f, 0.f};

  // ---- staging: position p covers rows p*64..p*64+63; per wave 8 rows ----
  const int srow8 = lane >> 3;   // row within 8-row group
  const int ssl = lane & 7;      // 16B slot (of 8 per 128 B row)
  const u16* gA[4];
  const u16* gB[2];
#pragma unroll
  for (int p = 0; p < 4; ++p) {
    const int row = p * 64 + wid * 8 + srow8;
    gA[p] = Abf + (size_t)row * K + ((ssl ^ (row & 7)) * 8);
  }
#pragma unroll
  for (int p = 0; p < 2; ++p) {
    const int row = p * 64 + wid * 8 + srow8;
    gB[p] = Bp + (size_t)row * K + ((ssl ^ (row & 7)) * 8);
  }

  auto stA = [&](int t, int s, int p) {
    gld_lds16(gA[p] + t * 64, &As[s][(p * 64 + wid * 8) * 64]);
  };
  auto stB = [&](int t, int s, int p) {
    gld_lds16(gB[p] + t * 64, &Bs[s][(p * 64 + wid * 8) * 64]);
  };

  // ---- fragment reads (A rows wid*32+i*16+fr; B rows j*16+fr) ----
  auto rdA = [&](int s, int i, int ks) -> bf16x8 {
    const int r = wid * 32 + i * 16 + fr;
    return *(const bf16x8*)&As[s][r * 64 + (((ks * 4 + fq) ^ (r & 7)) * 8)];
  };
  auto rdB = [&](int s, int j, int ks) -> bf16x8 {
    const int r = j * 16 + fr;
    return *(const bf16x8*)&Bs[s][r * 64 + (((ks * 4 + fq) ^ (r & 7)) * 8)];
  };

  static_assert((K >> 6) == 64, "nk = 64 K-tiles of 64");
  const int nk = K >> 6;

  // prologue: stage tiles 0 and 1 (6 loads each)
#pragma unroll
  for (int p = 0; p < 4; ++p) stA(0, 0, p);
#pragma unroll
  for (int p = 0; p < 2; ++p) stB(0, 0, p);
#pragma unroll
  for (int p = 0; p < 4; ++p) stA(1, 1, p);
#pragma unroll
  for (int p = 0; p < 2; ++p) stB(1, 1, p);
  asm volatile("s_waitcnt vmcnt(6)" ::: "memory");  // tile 0 landed
  __builtin_amdgcn_sched_barrier(0);
  __builtin_amdgcn_s_barrier();

  int buf = 0, nxt = 2;
  for (int t = 0; t < nk; ++t) {
    const bool st = (t + 2 < nk);
    bf16x8 av[2], bv[4];

    // ---- phase 0: ks=0, j 0..3 ----
    av[0] = rdA(buf, 0, 0); av[1] = rdA(buf, 1, 0);
    bv[0] = rdB(buf, 0, 0); bv[1] = rdB(buf, 1, 0);
    bv[2] = rdB(buf, 2, 0); bv[3] = rdB(buf, 3, 0);
    if (st) { stA(t + 2, nxt, 0); stA(t + 2, nxt, 1); }
    __builtin_amdgcn_s_barrier();
    asm volatile("s_waitcnt lgkmcnt(0)" ::: "memory");
    __builtin_amdgcn_sched_barrier(0);
    __builtin_amdgcn_s_setprio(1);
#pragma unroll
    for (int i = 0; i < 2; i++)
#pragma unroll
      for (int j = 0; j < 4; j++)
        acc[i][j] = __builtin_amdgcn_mfma_f32_16x16x32_bf16(av[i], bv[j], acc[i][j], 0, 0, 0);
    __builtin_amdgcn_s_setprio(0);
    __builtin_amdgcn_s_barrier();

    // ---- phase 1: ks=0, j 4..7 ----
    bv[0] = rdB(buf, 4, 0); bv[1] = rdB(buf, 5, 0);
    bv[2] = rdB(buf, 6, 0); bv[3] = rdB(buf, 7, 0);
    if (st) { stA(t + 2, nxt, 2); stA(t + 2, nxt, 3); }
    __builtin_amdgcn_s_barrier();
    asm volatile("s_waitcnt lgkmcnt(0)" ::: "memory");
    __builtin_amdgcn_sched_barrier(0);
    __builtin_amdgcn_s_setprio(1);
#pragma unroll
    for (int i = 0; i < 2; i++)
#pragma unroll
      for (int j = 0; j < 4; j++)
        acc[i][j + 4] = __builtin_amdgcn_mfma_f32_16x16x32_bf16(av[i], bv[j], acc[i][j + 4], 0, 0, 0);
    __builtin_amdgcn_s_setprio(0);
    __builtin_amdgcn_s_barrier();

    // ---- phase 2: ks=1, j 0..3 ----
    av[0] = rdA(buf, 0, 1); av[1] = rdA(buf, 1, 1);
    bv[0] = rdB(buf, 0, 1); bv[1] = rdB(buf, 1, 1);
    bv[2] = rdB(buf, 2, 1); bv[3] = rdB(buf, 3, 1);
    if (st) { stB(t + 2, nxt, 0); stB(t + 2, nxt, 1); }
    __builtin_amdgcn_s_barrier();
    asm volatile("s_waitcnt lgkmcnt(0)" ::: "memory");
    __builtin_amdgcn_sched_barrier(0);
    __builtin_amdgcn_s_setprio(1);
#pragma unroll
    for (int i = 0; i < 2; i++)
#pragma unroll
      for (int j = 0; j < 4; j++)
        acc[i][j] = __builtin_amdgcn_mfma_f32_16x16x32_bf16(av[i], bv[j], acc[i][j], 0, 0, 0);
    __builtin_amdgcn_s_setprio(0);
    __builtin_amdgcn_s_barrier();

    // ---- phase 3: ks=1, j 4..7 ----
    bv[0] = rdB(buf, 4, 1); bv[1] = rdB(buf, 5, 1);
    bv[2] = rdB(buf, 6, 1); bv[3] = rdB(buf, 7, 1);
    __builtin_amdgcn_s_barrier();
    asm volatile("s_waitcnt lgkmcnt(0)" ::: "memory");
    __builtin_amdgcn_sched_barrier(0);
    __builtin_amdgcn_s_setprio(1);
#pragma unroll
    for (int i = 0; i < 2; i++)
#pragma unroll
      for (int j = 0; j < 4; j++)
        acc[i][j + 4] = __builtin_amdgcn_mfma_f32_16x16x32_bf16(av[i], bv[j], acc[i][j + 4], 0, 0, 0);
    __builtin_amdgcn_s_setprio(0);

    // ---- tile end: counted vmcnt (never 0 mid-loop) ----
    if (st) {
      asm volatile("s_waitcnt vmcnt(6)" ::: "memory");  // tile t+1 landed
    } else {
      asm volatile("s_waitcnt vmcnt(0)" ::: "memory");
    }
    __builtin_amdgcn_sched_barrier(0);
    __builtin_amdgcn_s_barrier();
    buf = (buf == 2) ? 0 : buf + 1;
    nxt = (nxt == 2) ? 0 : nxt + 1;
  }

  // ----------------------------- epilogue -----------------------------
  if (MODE == M_QKV && which <= 1) {
    // fused RoPE (+quant for Q). Wave owns full head: d = j*16+fr.
#pragma unroll
    for (int i = 0; i < 2; i++) {
#pragma unroll
      for (int e = 0; e < 4; e++) {
        const int m = m0 + wid * 32 + i * 16 + fq * 4 + e;
        const int b = m >> 10, s = m & 1023;
        const float* cp = cosp + ((size_t)b * Ss + s) * HD;
        const float* sp2 = sinp + ((size_t)b * Ss + s) * HD;
        float r[8];
#pragma unroll
        for (int j = 0; j < 4; j++) {
          const float c = cp[j * 16 + fr];
          const float sv = sp2[j * 16 + fr];
          const float x1 = acc[i][j][e], x2 = acc[i][j + 4][e];
          r[j] = x1 * c - x2 * sv;       // d < 64
          r[j + 4] = x2 * c + x1 * sv;   // d+64 (cos/sin identical bitwise)
        }
        if (which == 0) {
          float mn = 0.f, mx = 0.f;
#pragma unroll
          for (int j = 0; j < 8; j++) { mn = fminf(mn, r[j]); mx = fmaxf(mx, r[j]); }
#pragma unroll
          for (int o = 1; o < 16; o <<= 1) {
            mn = fminf(mn, __shfl_xor(mn, o));
            mx = fmaxf(mx, __shfl_xor(mx, o));
          }
          const float rng = mx - mn;
          const float scale = (rng == 0.f) ? 1.f : rng / 255.f;
          const float zero = rintf(-mn / scale);
          const int hq = bx;
          u16* qp = Cq + ((size_t)(b * NH + hq) * Ss + s) * HD + fr;
#pragma unroll
          for (int j = 0; j < 8; j++) {
            const float qv = fminf(fmaxf(rintf(r[j] / scale) + zero, 0.f), 255.f);
            qp[j * 16] = f2bf((qv - zero) * scale);
          }
        } else {
          const int kh = bx - 32;
          float* kp = Ckf + ((size_t)(b * NKV + kh) * Ss + s) * HD + fr;
#pragma unroll
          for (int j = 0; j < 8; j++) kp[j * 16] = r[j];
        }
      }
    }
  } else {
#pragma unroll
    for (int i = 0; i < 2; i++) {
#pragma unroll
      for (int j = 0; j < 8; j++) {
        const int mb = m0 + wid * 32 + i * 16 + fq * 4;
        if (MODE == M_QKV) {
          // V: e-dim is s-contiguous -> float4 store
          const int b = mb >> 10, s = mb & 1023;
          const int h = bx - 40, d = j * 16 + fr;
          float4 v4 = {acc[i][j][0], acc[i][j][1], acc[i][j][2], acc[i][j][3]};
          *(float4*)&Cv[((size_t)(b * NKV + h) * HD + d) * Ss + s] = v4;
        } else {
          const int n = bx * 128 + j * 16 + fr;
#pragma unroll
          for (int e = 0; e < 4; e++)
            Cfo[(size_t)(mb + e) * HID + n] = acc[i][j][e];
        }
      }
    }
  }
}

// ---------------------------------------------------------------------------
// Fused causal attention (R13/R15, unchanged): 64 q-rows, 4 waves,
// K + V double-buffered in LDS with counted per-wave vmcnt (T4 pipeline).
// ---------------------------------------------------------------------------
__global__ __launch_bounds__(256) void fused_attn(
    const u16* __restrict__ qb,   // [B*NH*S][128]
    const u16* __restrict__ kb,   // [B*NKV*S][128]
    const u16* __restrict__ vTb,  // [B*NKV][128][1024]
    float* __restrict__ wout,     // [B*NH][1024][1024]
    u16* __restrict__ attnb) {    // [B*S][4096]
  __shared__ u16 Ks[2][64 * 128];  // 2 x 16 KB
  __shared__ u16 Vs[2][128 * 64];  // 2 x 16 KB
  __shared__ u16 plds[4][16 * 64]; // 8 KB (wave-private P tiles)
  __shared__ float scl_l[4][16];

  const int a = 15 - (int)(blockIdx.x >> 6);  // heavy blocks first
  const int bh = blockIdx.x & 63;
  const int b = bh >> 5, h = bh & 31;
  const int kv = h >> 2;
  const int tid = threadIdx.x;
  const int lane = tid & 63;
  const int wq = tid >> 6;
  const int fr = lane & 15, fq = lane >> 4;

  const int nt = a + 1;
  const int Q0 = a * 64;
  const int qw0 = Q0 + wq * 16;

  const u16* Kb = kb + (size_t)(b * NKV + kv) * Ss * HD;
  const u16* Vb = vTb + (size_t)(b * NKV + kv) * HD * Ss;
  float* wrow = wout + (size_t)bh * Ss * Ss;

  auto stageK = [&](int t, int s) {
#pragma unroll
    for (int c = 0; c < 4; ++c) {
      const int idx0 = (c * 4 + wq) * 64;
      const int idx = idx0 + lane;
      const int row = idx >> 4, sl = idx & 15;
      const int slot = sl ^ (row & 15);
      gld_lds16(Kb + (size_t)(t * 64 + row) * HD + slot * 8, &Ks[s][idx0 * 8]);
    }
  };
  auto stageV = [&](int t, int s) {
#pragma unroll
    for (int c = 0; c < 4; ++c) {
      const int idx0 = (c * 4 + wq) * 64;
      const int idx = idx0 + lane;
      const int d = idx >> 3, sl = idx & 7;
      const int slot = sl ^ (d & 7);
      gld_lds16(Vb + (size_t)d * Ss + t * 64 + slot * 8, &Vs[s][idx0 * 8]);
    }
  };

  // issue first K tile immediately — latency hides under zero-fill + Q loads
  stageK(0, 0);

  // zero-fill fully-masked columns [nt*64, 1024)
  if (a < 15) {
    const int base = 64 * nt;
    const int n4 = 16 * (15 - a);
#pragma unroll
    for (int r0 = 0; r0 < 4; ++r0) {
      const int row = Q0 + r0 * 16 + (tid >> 4);
      float4* wp = (float4*)&wrow[(size_t)row * Ss + base];
      for (int c = tid & 15; c < n4; c += 16) wp[c] = float4{0.f, 0.f, 0.f, 0.f};
    }
  }

  // Q fragments (reused by both sweeps)
  bf16x8 qf[4];
#pragma unroll
  for (int kk = 0; kk < 4; kk++)
    qf[kk] = *(const bf16x8*)&qb[((size_t)bh * Ss + qw0 + fr) * HD + kk * 32 + fq * 8];

  // ================= sweep 1: online m, l =================
  float m[4], l[4];
#pragma unroll
  for (int i = 0; i < 4; i++) { m[i] = -1e30f; l[i] = 0.f; }

  for (int t = 0; t < nt; ++t) {
    if (t + 1 < nt) {
      stageK(t + 1, (t + 1) & 1);
      asm volatile("s_waitcnt vmcnt(4)" ::: "memory");  // tile t landed
    } else {
      asm volatile("s_waitcnt vmcnt(0)" ::: "memory");
    }
    __builtin_amdgcn_sched_barrier(0);
    __builtin_amdgcn_s_barrier();
    const u16* Kt = &Ks[t & 1][0];

    f32x4 sa[4];
#pragma unroll
    for (int jn = 0; jn < 4; jn++) sa[jn] = (f32x4){0.f, 0.f, 0.f, 0.f};
#pragma unroll
    for (int kk = 0; kk < 4; ++kk) {
      bf16x8 kfv[4];
#pragma unroll
      for (int jn = 0; jn < 4; ++jn) {
        const int row = jn * 16 + fr;
        kfv[jn] = *(const bf16x8*)&Kt[row * 128 + (((kk * 4 + fq) ^ fr) * 8)];
      }
#pragma unroll
      for (int jn = 0; jn < 4; ++jn)
        sa[jn] = __builtin_amdgcn_mfma_f32_16x16x32_bf16(qf[kk], kfv[jn], sa[jn], 0, 0, 0);
    }

    const bool diag = (t == a);
#pragma unroll
    for (int e = 0; e < 4; ++e) {
      const int qrow = qw0 + fq * 4 + e;
      float sv[4];
      float rmax = -1e30f;
#pragma unroll
      for (int jn = 0; jn < 4; ++jn) {
        float s = sa[jn][e] * SCALING;
        if (diag && (t * 64 + jn * 16 + fr > qrow)) s = -1e30f;
        sv[jn] = s;
        rmax = fmaxf(rmax, s);
      }
#pragma unroll
      for (int o = 1; o < 16; o <<= 1) rmax = fmaxf(rmax, __shfl_xor(rmax, o));
      const float mn = fmaxf(m[e], rmax);
      const float cc = __expf(m[e] - mn);
      float rs = __expf(sv[0] - mn) + __expf(sv[1] - mn) +
                 __expf(sv[2] - mn) + __expf(sv[3] - mn);
#pragma unroll
      for (int o = 1; o < 16; o <<= 1) rs += __shfl_xor(rs, o);
      l[e] = l[e] * cc + rs;
      m[e] = mn;
    }
    __builtin_amdgcn_s_barrier();  // all reads of buf[t&1] done before reuse
  }

  float scl[4];
#pragma unroll
  for (int e = 0; e < 4; e++) scl[e] = 1.f / (255.f * l[e]);
  if (fr == 0) {
#pragma unroll
    for (int e = 0; e < 4; e++) scl_l[wq][fq * 4 + e] = scl[e];
  }

  // ================= sweep 2: emit w + PV =================
  f32x4 acc2[8];
#pragma unroll
  for (int j = 0; j < 8; j++) acc2[j] = (f32x4){0.f, 0.f, 0.f, 0.f};

  u16* pl = &plds[wq][0];
  const int wrrow = lane >> 2, wrq = lane & 3;
  const float sclr = scl_l[wq][wrrow];  // own-wave region, wave-ordered

  stageK(0, 0);
  stageV(0, 0);
  for (int t = 0; t < nt; ++t) {
    if (t + 1 < nt) {
      stageK(t + 1, (t + 1) & 1);
      stageV(t + 1, (t + 1) & 1);
      asm volatile("s_waitcnt vmcnt(8)" ::: "memory");  // tile t landed
    } else {
      asm volatile("s_waitcnt vmcnt(0)" ::: "memory");
    }
    __builtin_amdgcn_sched_barrier(0);
    __builtin_amdgcn_s_barrier();
    const u16* Kt = &Ks[t & 1][0];
    const u16* Vt = &Vs[t & 1][0];

    f32x4 sa[4];
#pragma unroll
    for (int jn = 0; jn < 4; jn++) sa[jn] = (f32x4){0.f, 0.f, 0.f, 0.f};
#pragma unroll
    for (int kk = 0; kk < 4; ++kk) {
      bf16x8 kfv[4];
#pragma unroll
      for (int jn = 0; jn < 4; ++jn) {
        const int row = jn * 16 + fr;
        kfv[jn] = *(const bf16x8*)&Kt[row * 128 + (((kk * 4 + fq) ^ fr) * 8)];
      }
#pragma unroll
      for (int jn = 0; jn < 4; ++jn)
        sa[jn] = __builtin_amdgcn_mfma_f32_16x16x32_bf16(qf[kk], kfv[jn], sa[jn], 0, 0, 0);
    }

    const bool diag = (t == a);
#pragma unroll
    for (int e = 0; e < 4; ++e) {
      const int qrow = qw0 + fq * 4 + e;
      const int r16 = fq * 4 + e;
#pragma unroll
      for (int jn = 0; jn < 4; ++jn) {
        const int kc = t * 64 + jn * 16 + fr;
        float qv = 0.f;
        if (!diag || kc <= qrow)
          qv = rintf(fminf(255.f * __expf(sa[jn][e] * SCALING - m[e]), 255.f));
        const int col = jn * 16 + fr;
        const int byte = r16 * 128 + (((col >> 3) ^ (r16 & 7)) * 16) + (col & 7) * 2;
        *(u16*)((char*)pl + byte) = f2bf(qv);  // ints 0..255 exact in bf16
      }
    }

    // vectorized w write (LDS readback, own-wave region)
    {
      const int s0 = (2 * wrq) ^ (wrrow & 7);
      const int s1 = (2 * wrq + 1) ^ (wrrow & 7);
      bf16x8 p0 = *(const bf16x8*)((char*)pl + wrrow * 128 + s0 * 16);
      bf16x8 p1 = *(const bf16x8*)((char*)pl + wrrow * 128 + s1 * 16);
      float* wp = &wrow[(size_t)(qw0 + wrrow) * Ss + t * 64 + wrq * 16];
      float4 o0, o1, o2, o3;
      o0.x = (float)p0[0] * sclr; o0.y = (float)p0[1] * sclr;
      o0.z = (float)p0[2] * sclr; o0.w = (float)p0[3] * sclr;
      o1.x = (float)p0[4] * sclr; o1.y = (float)p0[5] * sclr;
      o1.z = (float)p0[6] * sclr; o1.w = (float)p0[7] * sclr;
      o2.x = (float)p1[0] * sclr; o2.y = (float)p1[1] * sclr;
      o2.z = (float)p1[2] * sclr; o2.w = (float)p1[3] * sclr;
      o3.x = (float)p1[4] * sclr; o3.y = (float)p1[5] * sclr;
      o3.z = (float)p1[6] * sclr; o3.w = (float)p1[7] * sclr;
      ((float4*)wp)[0] = o0; ((float4*)wp)[1] = o1;
      ((float4*)wp)[2] = o2; ((float4*)wp)[3] = o3;
    }

    // PV: A = P ints (own LDS region), B = V^T (LDS)
#pragma unroll
    for (int kk2 = 0; kk2 < 2; ++kk2) {
      const bf16x8 pa = *(const bf16x8*)((char*)pl + fr * 128 + (((kk2 * 4 + fq) ^ (fr & 7)) * 16));
#pragma unroll
      for (int jn2 = 0; jn2 < 8; ++jn2) {
        const int d = jn2 * 16 + fr;
        const bf16x8 vb = *(const bf16x8*)&Vt[d * 64 + (((kk2 * 4 + fq) ^ (d & 7)) * 8)];
        acc2[jn2] = __builtin_amdgcn_mfma_f32_16x16x32_bf16(pa, vb, acc2[jn2], 0, 0, 0);
      }
    }
    __builtin_amdgcn_s_barrier();  // V reads done before buffer reuse
  }

  // epilogue: attn -> bf16 [B*S][NH*HD]
#pragma unroll
  for (int e = 0; e < 4; ++e) {
    const int qrow = qw0 + fq * 4 + e;
#pragma unroll
    for (int jn2 = 0; jn2 < 8; ++jn2)
      attnb[((size_t)b * Ss + qrow) * HID + h * HD + jn2 * 16 + fr] =
          f2bf(acc2[jn2][e] * scl[e]);
  }
}

// ---------------------------------------------------------------------------
// One-shot fp32 -> bf16 conversion of hs + all 4 weights (segmented grid).
constexpr int CB_HS = Bb * Ss * HID / 2048;       // 4096
constexpr int CB_WQ = NH * HD * HID / 2048;       // 8192
constexpr int CB_WK = NKV * HD * HID / 2048;      // 2048
constexpr int CB_WV = CB_WK;                      // 2048
constexpr int CB_WO = HID * NH * HD / 2048;       // 8192

__global__ __launch_bounds__(256) void convert_all(
    const float* __restrict__ hs, const float* __restrict__ wq,
    const float* __restrict__ wk, const float* __restrict__ wv,
    const float* __restrict__ wo,
    u16* __restrict__ hsb, u16* __restrict__ wqb, u16* __restrict__ wkb,
    u16* __restrict__ wvb, u16* __restrict__ wob) {
  const int bid = blockIdx.x;
  const float* src;
  u16* dst;
  int base;
  if (bid < CB_HS) { src = hs; dst = hsb; base = 0; }
  else if (bid < CB_HS + CB_WQ) { src = wq; dst = wqb; base = CB_HS; }
  else if (bid < CB_HS + CB_WQ + CB_WK) { src = wk; dst = wkb; base = CB_HS + CB_WQ; }
  else if (bid < CB_HS + CB_WQ + CB_WK + CB_WV) { src = wv; dst = wvb; base = CB_HS + CB_WQ + CB_WK; }
  else { src = wo; dst = wob; base = CB_HS + CB_WQ + CB_WK + CB_WV; }
  const int i = (bid - base) * 256 + threadIdx.x;
  float4 a = ((const float4*)src)[2 * i];
  float4 b = ((const float4*)src)[2 * i + 1];
  u16x8 t;
  t[0] = f2bf(a.x); t[1] = f2bf(a.y); t[2] = f2bf(a.z); t[3] = f2bf(a.w);
  t[4] = f2bf(b.x); t[5] = f2bf(b.y); t[6] = f2bf(b.z); t[7] = f2bf(b.w);
  ((u16x8*)dst)[i] = t;
}

// Per-(b,h,d) quant of v over S (vT rows) -> bf16. One block per row.
__global__ __launch_bounds__(256) void vquant(const float* __restrict__ vT,
                                              u16* __restrict__ vTb) {
  const float* p = vT + (size_t)blockIdx.x * Ss;
  const int t = threadIdx.x;
  float4 x = ((const float4*)p)[t];
  float mn = fminf(0.f, fminf(fminf(x.x, x.y), fminf(x.z, x.w)));
  float mx = fmaxf(0.f, fmaxf(fmaxf(x.x, x.y), fmaxf(x.z, x.w)));
#pragma unroll
  for (int o = 32; o; o >>= 1) {
    mn = fminf(mn, __shfl_xor(mn, o));
    mx = fmaxf(mx, __shfl_xor(mx, o));
  }
  __shared__ float smn[4], smx[4];
  const int wid = t >> 6, lane = t & 63;
  if (lane == 0) { smn[wid] = mn; smx[wid] = mx; }
  __syncthreads();
  mn = fminf(fminf(smn[0], smn[1]), fminf(smn[2], smn[3]));
  mx = fmaxf(fmaxf(smx[0], smx[1]), fmaxf(smx[2], smx[3]));
  float rng = mx - mn;
  float scale = (rng == 0.f) ? 1.f : rng / 255.f;
  float zero = rintf(-mn / scale);
  u16x4 o4;
  o4[0] = f2bf((fminf(fmaxf(rintf(x.x / scale) + zero, 0.f), 255.f) - zero) * scale);
  o4[1] = f2bf((fminf(fmaxf(rintf(x.y / scale) + zero, 0.f), 255.f) - zero) * scale);
  o4[2] = f2bf((fminf(fmaxf(rintf(x.z / scale) + zero, 0.f), 255.f) - zero) * scale);
  o4[3] = f2bf((fminf(fmaxf(rintf(x.w / scale) + zero, 0.f), 255.f) - zero) * scale);
  ((u16x4*)vTb)[(size_t)blockIdx.x * 256 + t] = o4;
}

// Mean of k over S per (b,h,d). One 1024-thread block per (b,h).
__global__ __launch_bounds__(1024) void kmean_kernel(const float* __restrict__ k,
                                                     float* __restrict__ kmean) {
  const int bh = blockIdx.x;
  const int d = threadIdx.x & 127;
  const int sl = threadIdx.x >> 7;
  const float* p = k + (size_t)bh * Ss * HD;
  float sum = 0.f;
  for (int s = sl; s < Ss; s += 8) sum += p[(size_t)s * HD + d];
  __shared__ float lds[8][128];
  lds[sl][d] = sum;
  __syncthreads();
  if (threadIdx.x < 128) {
    float t = 0.f;
#pragma unroll
    for (int i = 0; i < 8; i++) t += lds[i][threadIdx.x];
    kmean[bh * HD + threadIdx.x] = t * (1.f / 1024.f);
  }
}

// Subtract mean + per-row quant for k -> bf16. One wave per row.
__global__ __launch_bounds__(256) void k_subquant(const float* __restrict__ k,
                                                  u16* __restrict__ kb,
                                                  const float* __restrict__ kmean) {
  const int row = blockIdx.x * 4 + (threadIdx.x >> 6);
  const int lane = threadIdx.x & 63;
  const int bh = row >> 10;
  const float* p = k + (size_t)row * HD;
  float x1 = p[lane] - kmean[bh * HD + lane];
  float x2 = p[lane + 64] - kmean[bh * HD + lane + 64];
  float mn = fminf(0.f, fminf(x1, x2));
  float mx = fmaxf(0.f, fmaxf(x1, x2));
#pragma unroll
  for (int o = 32; o; o >>= 1) {
    mn = fminf(mn, __shfl_xor(mn, o));
    mx = fmaxf(mx, __shfl_xor(mx, o));
  }
  float rng = mx - mn;
  float scale = (rng == 0.f) ? 1.f : rng / 255.f;
  float zero = rintf(-mn / scale);
  float q1 = fminf(fmaxf(rintf(x1 / scale) + zero, 0.f), 255.f);
  float q2 = fminf(fmaxf(rintf(x2 / scale) + zero, 0.f), 255.f);
  kb[(size_t)row * HD + lane] = f2bf((q1 - zero) * scale);
  kb[(size_t)row * HD + lane + 64] = f2bf((q2 - zero) * scale);
}

// ---------------------------------------------------------------------------
extern "C" void kernel_launch(void* const* d_in, const int* in_sizes, int n_in,
                              void* d_out, int out_size, void* d_ws, size_t ws_size,
                              hipStream_t stream) {
  const float* hs = (const float*)d_in[0];
  const float* cosp = (const float*)d_in[1];
  const float* sinp = (const float*)d_in[2];
  const float* Wq = (const float*)d_in[4];
  const float* Wk = (const float*)d_in[5];
  const float* Wv = (const float*)d_in[6];
  const float* Wo = (const float*)d_in[7];

  float* out = (float*)d_out;
  float* wout = out + (size_t)Bb * Ss * HID;  // w output region (fp32)

  char* wsp = (char*)d_ws;
  auto alloc = [&](size_t bytes) {
    char* p = wsp;
    wsp += (bytes + 255) & ~(size_t)255;
    return p;
  };
  float* k     = (float*)alloc((size_t)Bb * NKV * Ss * HD * 4);  // 8.4 MB
  float* vT    = (float*)alloc((size_t)Bb * NKV * Ss * HD * 4);  // 8.4 MB
  float* kmean = (float*)alloc((size_t)Bb * NKV * HD * 4);
  u16* hsb = (u16*)alloc((size_t)Bb * Ss * HID * 2);
  u16* qb  = (u16*)alloc((size_t)Bb * NH * Ss * HD * 2);
  u16* kb  = (u16*)alloc((size_t)Bb * NKV * Ss * HD * 2);
  u16* vTb = (u16*)alloc((size_t)Bb * NKV * Ss * HD * 2);
  u16* Wqb = (u16*)alloc((size_t)NH * HD * HID * 2);
  u16* Wkb = (u16*)alloc((size_t)NKV * HD * HID * 2);
  u16* Wvb = (u16*)alloc((size_t)NKV * HD * HID * 2);
  u16* Wob = (u16*)alloc((size_t)HID * NH * HD * 2);
  u16* attnb = (u16*)alloc((size_t)Bb * Ss * HID * 2);           // 16.8 MB

  // fp32 -> bf16 conversions (single dispatch)
  convert_all<<<CB_HS + CB_WQ + CB_WK + CB_WV + CB_WO, 256, 0, stream>>>(
      hs, Wq, Wk, Wv, Wo, hsb, Wqb, Wkb, Wvb, Wob);

  // fused Q/K/V projection + RoPE + quant(q): 256x128 tiles, 48 x 8 blocks
  mfma_gemm<M_QKV, HID><<<dim3(48, 8), 512, 0, stream>>>(
      hsb, Wqb, Wkb, Wvb, qb, k, vT, nullptr, cosp, sinp);

  // V quant (independent of k-path)
  vquant<<<Bb * NKV * HD, 256, 0, stream>>>(vT, vTb);
  kmean_kernel<<<Bb * NKV, 1024, 0, stream>>>(k, kmean);
  k_subquant<<<(Bb * NKV * Ss) / 4, 256, 0, stream>>>(k, kb, kmean);

  // fused scores+softmax+quant(w)+PV (1024 blocks, heavy first, pipelined)
  fused_attn<<<dim3(1024), 256, 0, stream>>>(qb, kb, vTb, wout, attnb);

  // out = attn @ Wo^T (256x128 tiles, 32 x 8 = 256 blocks = 1/CU)
  mfma_gemm<M_OUT, HID><<<dim3(32, 8), 512, 0, stream>>>(
      attnb, Wob, nullptr, nullptr, nullptr, nullptr, nullptr, out,
      nullptr, nullptr);
}

// Round 17
// 414.707 us; speedup vs baseline: 1.0324x; 1.0324x over previous
//
#include <hip/hip_runtime.h>
#include <math.h>
#include <stdint.h>

typedef unsigned int u32;
typedef unsigned short u16;
typedef __bf16 bf16x8 __attribute__((ext_vector_type(8)));
typedef float f32x4 __attribute__((ext_vector_type(4)));
typedef unsigned short u16x8 __attribute__((ext_vector_type(8)));
typedef unsigned short u16x4 __attribute__((ext_vector_type(4)));

constexpr int   Bb  = 2;
constexpr int   Ss  = 1024;
constexpr int   HID = 4096;
constexpr int   NH  = 32;
constexpr int   NKV = 8;
constexpr int   HD  = 128;
constexpr float SCALING = 0.0883883476483184405501f; // 128^-0.5

enum { M_QKV = 0, M_OUT = 3 };

// fp32 -> bf16 RTNE (bit trick; finite values only here)
__device__ __forceinline__ u16 f2bf(float f) {
  u32 u = __builtin_bit_cast(u32, f);
  u = u + 0x7fffu + ((u >> 16) & 1u);
  return (u16)(u >> 16);
}

// async global->LDS, 16B per lane (offset arg always 0 — verified semantics;
// compile-time global offsets are expressed as pointer arithmetic instead)
__device__ __forceinline__ void gld_lds16(const void* g, void* l) {
  __builtin_amdgcn_global_load_lds(
      (const __attribute__((address_space(1))) u32*)(uintptr_t)g,
      (__attribute__((address_space(3))) u32*)(uintptr_t)l, 16, 0, 0);
}

// ---------------------------------------------------------------------------
// bf16 MFMA GEMM, wave-tile 64x128, BM=128 BN=256 BK=32, 3-buffer pipeline.
// K-loop unrolled x3 so buffer indices are literals; per-lane global pointers
// hoisted (advance +96 elems per triple; per-tile offset is compile-time
// pointer arithmetic the compiler folds into the instruction immediate).
// Fragment-read addressing collapsed to one per-lane base + literal offsets
// (swizzle slot (r>>1)&3 == (fr>>1)&3 for all fragment rows — invariant).
// Counted vmcnt(6), never 0 mid-loop.
// Epilogues: fused RoPE+quant(q)/RoPE(k) for M_QKV, float4 V, plain OUT.
// ---------------------------------------------------------------------------
template <int MODE, int K>
__global__ __launch_bounds__(256, 2) void mfma_gemm(
    const u16* __restrict__ Abf_g,
    const u16* __restrict__ B0, const u16* __restrict__ B1,
    const u16* __restrict__ B2,
    u16* __restrict__ Cq, float* __restrict__ Ckf, float* __restrict__ Cv,
    float* __restrict__ Cfo,
    const float* __restrict__ cosp, const float* __restrict__ sinp) {
  __shared__ u16 As[3][128 * 32];  // 3 x 8 KB
  __shared__ u16 Bs[3][256 * 32];  // 3 x 16 KB

  const int tid = threadIdx.x;
  const int lane = tid & 63;
  const int wid = tid >> 6;        // 0..3
  const int wr = wid >> 1;         // 0..1
  const int wc = wid & 1;          // 0..1
  const int fr = lane & 15;
  const int fq = lane >> 4;
  const int wid16 = wid * 16;

  const int bx = blockIdx.x;
  const int m0 = blockIdx.y * 128;
  int nloc = 0;

  const u16* Abf = Abf_g + (size_t)m0 * K;
  const u16* Bp = nullptr;
  int which = 0;

  if (MODE == M_QKV) {
    if (bx < 16)      { which = 0; Bp = B0 + (size_t)bx * 256 * K;        nloc = bx * 256; }
    else if (bx < 20) { which = 1; Bp = B1 + (size_t)(bx - 16) * 256 * K; nloc = (bx - 16) * 256; }
    else              { which = 2; Bp = B2 + (size_t)(bx - 20) * 256 * K; nloc = (bx - 20) * 256; }
  } else {  // M_OUT
    Bp = B0 + (size_t)bx * 256 * K;
    nloc = bx * 256;
  }

  f32x4 acc[4][8];
#pragma unroll
  for (int i = 0; i < 4; i++)
#pragma unroll
    for (int j = 0; j < 8; j++) acc[i][j] = (f32x4){0.f, 0.f, 0.f, 0.f};

  // ---- per-lane staging pointers (computed once; +96 elems per triple) ----
  const int prow = wid16 + (lane >> 2);
  const int psl = lane & 3;
  const u16* gA[2];
  const u16* gB[4];
#pragma unroll
  for (int e = 0; e < 2; ++e) {
    const int row = e * 64 + prow;
    gA[e] = Abf + (size_t)row * K + ((psl ^ ((row >> 1) & 3)) * 8);
  }
#pragma unroll
  for (int e = 0; e < 4; ++e) {
    const int row = e * 64 + prow;
    gB[e] = Bp + (size_t)row * K + ((psl ^ ((row >> 1) & 3)) * 8);
  }

  // ---- per-lane fragment-read bases (swizzle slot invariant across frags) ----
  const int swz8 = (fq ^ ((fr >> 1) & 3)) * 8;
  const int aBase = (wr * 64 + fr) * 32 + swz8;    // + i*512  (+BUF literal)
  const int bBase = (wc * 128 + fr) * 32 + swz8;   // + j*512, +2048 phase 1

#define STA(S, E, SOFF) gld_lds16(gA[E] + (SOFF) * 32, &As[S][((E) * 64 + wid16) * 32])
#define STB(S, E, SOFF) gld_lds16(gB[E] + (SOFF) * 32, &Bs[S][((E) * 64 + wid16) * 32])

#define GTILE(BUF, NXT, SOFF, ST, VM)                                          \
  {                                                                            \
    bf16x8 av[4], bv[4];                                                       \
    _Pragma("unroll") for (int i = 0; i < 4; ++i)                              \
        av[i] = *(const bf16x8*)&As[BUF][aBase + i * 512];                     \
    _Pragma("unroll") for (int j = 0; j < 4; ++j)                              \
        bv[j] = *(const bf16x8*)&Bs[BUF][bBase + j * 512];                     \
    if (ST) { STA(NXT, 0, SOFF); STA(NXT, 1, SOFF); STB(NXT, 0, SOFF); }       \
    __builtin_amdgcn_s_barrier();                                              \
    asm volatile("s_waitcnt lgkmcnt(0)" ::: "memory");                         \
    __builtin_amdgcn_sched_barrier(0);                                         \
    __builtin_amdgcn_s_setprio(1);                                             \
    _Pragma("unroll") for (int i = 0; i < 4; i++)                              \
        _Pragma("unroll") for (int j = 0; j < 4; j++)                          \
            acc[i][j] = __builtin_amdgcn_mfma_f32_16x16x32_bf16(               \
                av[i], bv[j], acc[i][j], 0, 0, 0);                             \
    __builtin_amdgcn_s_setprio(0);                                             \
    _Pragma("unroll") for (int j = 0; j < 4; ++j)                              \
        bv[j] = *(const bf16x8*)&Bs[BUF][bBase + 2048 + j * 512];              \
    if (ST) { STB(NXT, 1, SOFF); STB(NXT, 2, SOFF); STB(NXT, 3, SOFF); }       \
    __builtin_amdgcn_s_barrier();                                              \
    asm volatile("s_waitcnt lgkmcnt(0)" ::: "memory");                         \
    __builtin_amdgcn_sched_barrier(0);                                         \
    __builtin_amdgcn_s_setprio(1);                                             \
    _Pragma("unroll") for (int i = 0; i < 4; i++)                              \
        _Pragma("unroll") for (int j = 0; j < 4; j++)                          \
            acc[i][j + 4] = __builtin_amdgcn_mfma_f32_16x16x32_bf16(           \
                av[i], bv[j], acc[i][j + 4], 0, 0, 0);                         \
    __builtin_amdgcn_s_setprio(0);                                             \
    asm volatile("s_waitcnt vmcnt(" #VM ")" ::: "memory");                     \
    __builtin_amdgcn_sched_barrier(0);                                         \
    __builtin_amdgcn_s_barrier();                                              \
  }

  // prologue: stage tiles 0 (buf0) and 1 (buf1)
  STA(0, 0, 0); STA(0, 1, 0); STB(0, 0, 0); STB(0, 1, 0); STB(0, 2, 0); STB(0, 3, 0);
  STA(1, 0, 1); STA(1, 1, 1); STB(1, 0, 1); STB(1, 1, 1); STB(1, 2, 1); STB(1, 3, 1);
  asm volatile("s_waitcnt vmcnt(6)" ::: "memory");  // tile 0 landed
  __builtin_amdgcn_sched_barrier(0);
  __builtin_amdgcn_s_barrier();

  static_assert((K >> 5) == 128, "K-loop layout assumes nk=128");
  for (int kb = 0; kb < 42; ++kb) {  // tiles 3kb..3kb+2, stage 3kb+2..3kb+4
    GTILE(0, 2, 2, true, 6)
    GTILE(1, 0, 3, true, 6)
    GTILE(2, 1, 4, true, 6)
#pragma unroll
    for (int e = 0; e < 2; ++e) gA[e] += 96;
#pragma unroll
    for (int e = 0; e < 4; ++e) gB[e] += 96;
  }
  GTILE(0, 0, 0, false, 0)  // tile 126
  GTILE(1, 0, 0, false, 0)  // tile 127

#undef GTILE
#undef STA
#undef STB

  // ----------------------------- epilogue -----------------------------
  if (MODE == M_QKV && which <= 1) {
    // fused RoPE (+quant for Q). Wave owns full head: d = j*16+fr.
#pragma unroll
    for (int i = 0; i < 4; i++) {
#pragma unroll
      for (int e = 0; e < 4; e++) {
        const int m = m0 + wr * 64 + i * 16 + fq * 4 + e;
        const int b = m >> 10, s = m & 1023;
        const float* cp = cosp + ((size_t)b * Ss + s) * HD;
        const float* sp2 = sinp + ((size_t)b * Ss + s) * HD;
        float r[8];
#pragma unroll
        for (int j = 0; j < 4; j++) {
          const float c = cp[j * 16 + fr];
          const float sv = sp2[j * 16 + fr];
          const float x1 = acc[i][j][e], x2 = acc[i][j + 4][e];
          r[j] = x1 * c - x2 * sv;       // d < 64
          r[j + 4] = x2 * c + x1 * sv;   // d+64 (cos/sin identical bitwise)
        }
        if (which == 0) {
          float mn = 0.f, mx = 0.f;
#pragma unroll
          for (int j = 0; j < 8; j++) { mn = fminf(mn, r[j]); mx = fmaxf(mx, r[j]); }
#pragma unroll
          for (int o = 1; o < 16; o <<= 1) {
            mn = fminf(mn, __shfl_xor(mn, o));
            mx = fmaxf(mx, __shfl_xor(mx, o));
          }
          const float rng = mx - mn;
          const float scale = (rng == 0.f) ? 1.f : rng / 255.f;
          const float zero = rintf(-mn / scale);
          const int hq = bx * 2 + wc;
          u16* qp = Cq + ((size_t)(b * NH + hq) * Ss + s) * HD + fr;
#pragma unroll
          for (int j = 0; j < 8; j++) {
            const float qv = fminf(fmaxf(rintf(r[j] / scale) + zero, 0.f), 255.f);
            qp[j * 16] = f2bf((qv - zero) * scale);
          }
        } else {
          const int kh = (bx - 16) * 2 + wc;
          float* kp = Ckf + ((size_t)(b * NKV + kh) * Ss + s) * HD + fr;
#pragma unroll
          for (int j = 0; j < 8; j++) kp[j * 16] = r[j];
        }
      }
    }
  } else {
#pragma unroll
    for (int i = 0; i < 4; i++) {
#pragma unroll
      for (int j = 0; j < 8; j++) {
        const int n = nloc + wc * 128 + j * 16 + fr;
        const int mb = m0 + wr * 64 + i * 16 + fq * 4;
        if (MODE == M_QKV) {
          // V: e-dim is s-contiguous -> float4 store
          const int b = mb >> 10, s = mb & 1023, h = n >> 7, d = n & 127;
          float4 v4 = {acc[i][j][0], acc[i][j][1], acc[i][j][2], acc[i][j][3]};
          *(float4*)&Cv[((size_t)(b * NKV + h) * HD + d) * Ss + s] = v4;
        } else {
#pragma unroll
          for (int e = 0; e < 4; e++)
            Cfo[(size_t)(mb + e) * HID + n] = acc[i][j][e];
        }
      }
    }
  }
}

// ---------------------------------------------------------------------------
// Fused causal attention (R9/R11/R13 structure): 64 q-rows, 4 waves,
// K + V double-buffered in LDS with counted per-wave vmcnt (T4 pipeline).
// ---------------------------------------------------------------------------
__global__ __launch_bounds__(256) void fused_attn(
    const u16* __restrict__ qb,   // [B*NH*S][128]
    const u16* __restrict__ kb,   // [B*NKV*S][128]
    const u16* __restrict__ vTb,  // [B*NKV][128][1024]
    float* __restrict__ wout,     // [B*NH][1024][1024]
    u16* __restrict__ attnb) {    // [B*S][4096]
  __shared__ u16 Ks[2][64 * 128];  // 2 x 16 KB
  __shared__ u16 Vs[2][128 * 64];  // 2 x 16 KB
  __shared__ u16 plds[4][16 * 64]; // 8 KB (wave-private P tiles)
  __shared__ float scl_l[4][16];

  const int a = 15 - (int)(blockIdx.x >> 6);  // heavy blocks first
  const int bh = blockIdx.x & 63;
  const int b = bh >> 5, h = bh & 31;
  const int kv = h >> 2;
  const int tid = threadIdx.x;
  const int lane = tid & 63;
  const int wq = tid >> 6;
  const int fr = lane & 15, fq = lane >> 4;

  const int nt = a + 1;
  const int Q0 = a * 64;
  const int qw0 = Q0 + wq * 16;

  const u16* Kb = kb + (size_t)(b * NKV + kv) * Ss * HD;
  const u16* Vb = vTb + (size_t)(b * NKV + kv) * HD * Ss;
  float* wrow = wout + (size_t)bh * Ss * Ss;

  auto stageK = [&](int t, int s) {
#pragma unroll
    for (int c = 0; c < 4; ++c) {
      const int idx0 = (c * 4 + wq) * 64;
      const int idx = idx0 + lane;
      const int row = idx >> 4, sl = idx & 15;
      const int slot = sl ^ (row & 15);
      gld_lds16(Kb + (size_t)(t * 64 + row) * HD + slot * 8, &Ks[s][idx0 * 8]);
    }
  };
  auto stageV = [&](int t, int s) {
#pragma unroll
    for (int c = 0; c < 4; ++c) {
      const int idx0 = (c * 4 + wq) * 64;
      const int idx = idx0 + lane;
      const int d = idx >> 3, sl = idx & 7;
      const int slot = sl ^ (d & 7);
      gld_lds16(Vb + (size_t)d * Ss + t * 64 + slot * 8, &Vs[s][idx0 * 8]);
    }
  };

  // issue first K tile immediately — latency hides under zero-fill + Q loads
  stageK(0, 0);

  // zero-fill fully-masked columns [nt*64, 1024)
  if (a < 15) {
    const int base = 64 * nt;
    const int n4 = 16 * (15 - a);
#pragma unroll
    for (int r0 = 0; r0 < 4; ++r0) {
      const int row = Q0 + r0 * 16 + (tid >> 4);
      float4* wp = (float4*)&wrow[(size_t)row * Ss + base];
      for (int c = tid & 15; c < n4; c += 16) wp[c] = float4{0.f, 0.f, 0.f, 0.f};
    }
  }

  // Q fragments (reused by both sweeps)
  bf16x8 qf[4];
#pragma unroll
  for (int kk = 0; kk < 4; kk++)
    qf[kk] = *(const bf16x8*)&qb[((size_t)bh * Ss + qw0 + fr) * HD + kk * 32 + fq * 8];

  // ================= sweep 1: online m, l =================
  float m[4], l[4];
#pragma unroll
  for (int i = 0; i < 4; i++) { m[i] = -1e30f; l[i] = 0.f; }

  for (int t = 0; t < nt; ++t) {
    if (t + 1 < nt) {
      stageK(t + 1, (t + 1) & 1);
      asm volatile("s_waitcnt vmcnt(4)" ::: "memory");  // tile t landed
    } else {
      asm volatile("s_waitcnt vmcnt(0)" ::: "memory");
    }
    __builtin_amdgcn_sched_barrier(0);
    __builtin_amdgcn_s_barrier();
    const u16* Kt = &Ks[t & 1][0];

    f32x4 sa[4];
#pragma unroll
    for (int jn = 0; jn < 4; jn++) sa[jn] = (f32x4){0.f, 0.f, 0.f, 0.f};
#pragma unroll
    for (int kk = 0; kk < 4; ++kk) {
      bf16x8 kfv[4];
#pragma unroll
      for (int jn = 0; jn < 4; ++jn) {
        const int row = jn * 16 + fr;
        kfv[jn] = *(const bf16x8*)&Kt[row * 128 + (((kk * 4 + fq) ^ fr) * 8)];
      }
#pragma unroll
      for (int jn = 0; jn < 4; ++jn)
        sa[jn] = __builtin_amdgcn_mfma_f32_16x16x32_bf16(qf[kk], kfv[jn], sa[jn], 0, 0, 0);
    }

    const bool diag = (t == a);
#pragma unroll
    for (int e = 0; e < 4; ++e) {
      const int qrow = qw0 + fq * 4 + e;
      float sv[4];
      float rmax = -1e30f;
#pragma unroll
      for (int jn = 0; jn < 4; ++jn) {
        float s = sa[jn][e] * SCALING;
        if (diag && (t * 64 + jn * 16 + fr > qrow)) s = -1e30f;
        sv[jn] = s;
        rmax = fmaxf(rmax, s);
      }
#pragma unroll
      for (int o = 1; o < 16; o <<= 1) rmax = fmaxf(rmax, __shfl_xor(rmax, o));
      const float mn = fmaxf(m[e], rmax);
      const float cc = __expf(m[e] - mn);
      float rs = __expf(sv[0] - mn) + __expf(sv[1] - mn) +
                 __expf(sv[2] - mn) + __expf(sv[3] - mn);
#pragma unroll
      for (int o = 1; o < 16; o <<= 1) rs += __shfl_xor(rs, o);
      l[e] = l[e] * cc + rs;
      m[e] = mn;
    }
    __builtin_amdgcn_s_barrier();  // all reads of buf[t&1] done before reuse
  }

  float scl[4];
#pragma unroll
  for (int e = 0; e < 4; e++) scl[e] = 1.f / (255.f * l[e]);
  if (fr == 0) {
#pragma unroll
    for (int e = 0; e < 4; e++) scl_l[wq][fq * 4 + e] = scl[e];
  }

  // ================= sweep 2: emit w + PV =================
  f32x4 acc2[8];
#pragma unroll
  for (int j = 0; j < 8; j++) acc2[j] = (f32x4){0.f, 0.f, 0.f, 0.f};

  u16* pl = &plds[wq][0];
  const int wrrow = lane >> 2, wrq = lane & 3;
  const float sclr = scl_l[wq][wrrow];  // own-wave region, wave-ordered

  stageK(0, 0);
  stageV(0, 0);
  for (int t = 0; t < nt; ++t) {
    if (t + 1 < nt) {
      stageK(t + 1, (t + 1) & 1);
      stageV(t + 1, (t + 1) & 1);
      asm volatile("s_waitcnt vmcnt(8)" ::: "memory");  // tile t landed
    } else {
      asm volatile("s_waitcnt vmcnt(0)" ::: "memory");
    }
    __builtin_amdgcn_sched_barrier(0);
    __builtin_amdgcn_s_barrier();
    const u16* Kt = &Ks[t & 1][0];
    const u16* Vt = &Vs[t & 1][0];

    f32x4 sa[4];
#pragma unroll
    for (int jn = 0; jn < 4; jn++) sa[jn] = (f32x4){0.f, 0.f, 0.f, 0.f};
#pragma unroll
    for (int kk = 0; kk < 4; ++kk) {
      bf16x8 kfv[4];
#pragma unroll
      for (int jn = 0; jn < 4; ++jn) {
        const int row = jn * 16 + fr;
        kfv[jn] = *(const bf16x8*)&Kt[row * 128 + (((kk * 4 + fq) ^ fr) * 8)];
      }
#pragma unroll
      for (int jn = 0; jn < 4; ++jn)
        sa[jn] = __builtin_amdgcn_mfma_f32_16x16x32_bf16(qf[kk], kfv[jn], sa[jn], 0, 0, 0);
    }

    const bool diag = (t == a);
#pragma unroll
    for (int e = 0; e < 4; ++e) {
      const int qrow = qw0 + fq * 4 + e;
      const int r16 = fq * 4 + e;
#pragma unroll
      for (int jn = 0; jn < 4; ++jn) {
        const int kc = t * 64 + jn * 16 + fr;
        float qv = 0.f;
        if (!diag || kc <= qrow)
          qv = rintf(fminf(255.f * __expf(sa[jn][e] * SCALING - m[e]), 255.f));
        const int col = jn * 16 + fr;
        const int byte = r16 * 128 + (((col >> 3) ^ (r16 & 7)) * 16) + (col & 7) * 2;
        *(u16*)((char*)pl + byte) = f2bf(qv);  // ints 0..255 exact in bf16
      }
    }

    // vectorized w write (LDS readback, own-wave region)
    {
      const int s0 = (2 * wrq) ^ (wrrow & 7);
      const int s1 = (2 * wrq + 1) ^ (wrrow & 7);
      bf16x8 p0 = *(const bf16x8*)((char*)pl + wrrow * 128 + s0 * 16);
      bf16x8 p1 = *(const bf16x8*)((char*)pl + wrrow * 128 + s1 * 16);
      float* wp = &wrow[(size_t)(qw0 + wrrow) * Ss + t * 64 + wrq * 16];
      float4 o0, o1, o2, o3;
      o0.x = (float)p0[0] * sclr; o0.y = (float)p0[1] * sclr;
      o0.z = (float)p0[2] * sclr; o0.w = (float)p0[3] * sclr;
      o1.x = (float)p0[4] * sclr; o1.y = (float)p0[5] * sclr;
      o1.z = (float)p0[6] * sclr; o1.w = (float)p0[7] * sclr;
      o2.x = (float)p1[0] * sclr; o2.y = (float)p1[1] * sclr;
      o2.z = (float)p1[2] * sclr; o2.w = (float)p1[3] * sclr;
      o3.x = (float)p1[4] * sclr; o3.y = (float)p1[5] * sclr;
      o3.z = (float)p1[6] * sclr; o3.w = (float)p1[7] * sclr;
      ((float4*)wp)[0] = o0; ((float4*)wp)[1] = o1;
      ((float4*)wp)[2] = o2; ((float4*)wp)[3] = o3;
    }

    // PV: A = P ints (own LDS region), B = V^T (LDS)
#pragma unroll
    for (int kk2 = 0; kk2 < 2; ++kk2) {
      const bf16x8 pa = *(const bf16x8*)((char*)pl + fr * 128 + (((kk2 * 4 + fq) ^ (fr & 7)) * 16));
#pragma unroll
      for (int jn2 = 0; jn2 < 8; ++jn2) {
        const int d = jn2 * 16 + fr;
        const bf16x8 vb = *(const bf16x8*)&Vt[d * 64 + (((kk2 * 4 + fq) ^ (d & 7)) * 8)];
        acc2[jn2] = __builtin_amdgcn_mfma_f32_16x16x32_bf16(pa, vb, acc2[jn2], 0, 0, 0);
      }
    }
    __builtin_amdgcn_s_barrier();  // V reads done before buffer reuse
  }

  // epilogue: attn -> bf16 [B*S][NH*HD]
#pragma unroll
  for (int e = 0; e < 4; ++e) {
    const int qrow = qw0 + fq * 4 + e;
#pragma unroll
    for (int jn2 = 0; jn2 < 8; ++jn2)
      attnb[((size_t)b * Ss + qrow) * HID + h * HD + jn2 * 16 + fr] =
          f2bf(acc2[jn2][e] * scl[e]);
  }
}

// ---------------------------------------------------------------------------
// One-shot fp32 -> bf16 conversion of hs + all 4 weights (segmented grid).
constexpr int CB_HS = Bb * Ss * HID / 2048;       // 4096
constexpr int CB_WQ = NH * HD * HID / 2048;       // 8192
constexpr int CB_WK = NKV * HD * HID / 2048;      // 2048
constexpr int CB_WV = CB_WK;                      // 2048
constexpr int CB_WO = HID * NH * HD / 2048;       // 8192

__global__ __launch_bounds__(256) void convert_all(
    const float* __restrict__ hs, const float* __restrict__ wq,
    const float* __restrict__ wk, const float* __restrict__ wv,
    const float* __restrict__ wo,
    u16* __restrict__ hsb, u16* __restrict__ wqb, u16* __restrict__ wkb,
    u16* __restrict__ wvb, u16* __restrict__ wob) {
  const int bid = blockIdx.x;
  const float* src;
  u16* dst;
  int base;
  if (bid < CB_HS) { src = hs; dst = hsb; base = 0; }
  else if (bid < CB_HS + CB_WQ) { src = wq; dst = wqb; base = CB_HS; }
  else if (bid < CB_HS + CB_WQ + CB_WK) { src = wk; dst = wkb; base = CB_HS + CB_WQ; }
  else if (bid < CB_HS + CB_WQ + CB_WK + CB_WV) { src = wv; dst = wvb; base = CB_HS + CB_WQ + CB_WK; }
  else { src = wo; dst = wob; base = CB_HS + CB_WQ + CB_WK + CB_WV; }
  const int i = (bid - base) * 256 + threadIdx.x;
  float4 a = ((const float4*)src)[2 * i];
  float4 b = ((const float4*)src)[2 * i + 1];
  u16x8 t;
  t[0] = f2bf(a.x); t[1] = f2bf(a.y); t[2] = f2bf(a.z); t[3] = f2bf(a.w);
  t[4] = f2bf(b.x); t[5] = f2bf(b.y); t[6] = f2bf(b.z); t[7] = f2bf(b.w);
  ((u16x8*)dst)[i] = t;
}

// Per-(b,h,d) quant of v over S (vT rows) -> bf16. One block per row.
__global__ __launch_bounds__(256) void vquant(const float* __restrict__ vT,
                                              u16* __restrict__ vTb) {
  const float* p = vT + (size_t)blockIdx.x * Ss;
  const int t = threadIdx.x;
  float4 x = ((const float4*)p)[t];
  float mn = fminf(0.f, fminf(fminf(x.x, x.y), fminf(x.z, x.w)));
  float mx = fmaxf(0.f, fmaxf(fmaxf(x.x, x.y), fmaxf(x.z, x.w)));
#pragma unroll
  for (int o = 32; o; o >>= 1) {
    mn = fminf(mn, __shfl_xor(mn, o));
    mx = fmaxf(mx, __shfl_xor(mx, o));
  }
  __shared__ float smn[4], smx[4];
  const int wid = t >> 6, lane = t & 63;
  if (lane == 0) { smn[wid] = mn; smx[wid] = mx; }
  __syncthreads();
  mn = fminf(fminf(smn[0], smn[1]), fminf(smn[2], smn[3]));
  mx = fmaxf(fmaxf(smx[0], smx[1]), fmaxf(smx[2], smx[3]));
  float rng = mx - mn;
  float scale = (rng == 0.f) ? 1.f : rng / 255.f;
  float zero = rintf(-mn / scale);
  u16x4 o4;
  o4[0] = f2bf((fminf(fmaxf(rintf(x.x / scale) + zero, 0.f), 255.f) - zero) * scale);
  o4[1] = f2bf((fminf(fmaxf(rintf(x.y / scale) + zero, 0.f), 255.f) - zero) * scale);
  o4[2] = f2bf((fminf(fmaxf(rintf(x.z / scale) + zero, 0.f), 255.f) - zero) * scale);
  o4[3] = f2bf((fminf(fmaxf(rintf(x.w / scale) + zero, 0.f), 255.f) - zero) * scale);
  ((u16x4*)vTb)[(size_t)blockIdx.x * 256 + t] = o4;
}

// Mean of k over S per (b,h,d). One 1024-thread block per (b,h).
__global__ __launch_bounds__(1024) void kmean_kernel(const float* __restrict__ k,
                                                     float* __restrict__ kmean) {
  const int bh = blockIdx.x;
  const int d = threadIdx.x & 127;
  const int sl = threadIdx.x >> 7;
  const float* p = k + (size_t)bh * Ss * HD;
  float sum = 0.f;
  for (int s = sl; s < Ss; s += 8) sum += p[(size_t)s * HD + d];
  __shared__ float lds[8][128];
  lds[sl][d] = sum;
  __syncthreads();
  if (threadIdx.x < 128) {
    float t = 0.f;
#pragma unroll
    for (int i = 0; i < 8; i++) t += lds[i][threadIdx.x];
    kmean[bh * HD + threadIdx.x] = t * (1.f / 1024.f);
  }
}

// Subtract mean + per-row quant for k -> bf16. One wave per row.
__global__ __launch_bounds__(256) void k_subquant(const float* __restrict__ k,
                                                  u16* __restrict__ kb,
                                                  const float* __restrict__ kmean) {
  const int row = blockIdx.x * 4 + (threadIdx.x >> 6);
  const int lane = threadIdx.x & 63;
  const int bh = row >> 10;
  const float* p = k + (size_t)row * HD;
  float x1 = p[lane] - kmean[bh * HD + lane];
  float x2 = p[lane + 64] - kmean[bh * HD + lane + 64];
  float mn = fminf(0.f, fminf(x1, x2));
  float mx = fmaxf(0.f, fmaxf(x1, x2));
#pragma unroll
  for (int o = 32; o; o >>= 1) {
    mn = fminf(mn, __shfl_xor(mn, o));
    mx = fmaxf(mx, __shfl_xor(mx, o));
  }
  float rng = mx - mn;
  float scale = (rng == 0.f) ? 1.f : rng / 255.f;
  float zero = rintf(-mn / scale);
  float q1 = fminf(fmaxf(rintf(x1 / scale) + zero, 0.f), 255.f);
  float q2 = fminf(fmaxf(rintf(x2 / scale) + zero, 0.f), 255.f);
  kb[(size_t)row * HD + lane] = f2bf((q1 - zero) * scale);
  kb[(size_t)row * HD + lane + 64] = f2bf((q2 - zero) * scale);
}

// ---------------------------------------------------------------------------
extern "C" void kernel_launch(void* const* d_in, const int* in_sizes, int n_in,
                              void* d_out, int out_size, void* d_ws, size_t ws_size,
                              hipStream_t stream) {
  const float* hs = (const float*)d_in[0];
  const float* cosp = (const float*)d_in[1];
  const float* sinp = (const float*)d_in[2];
  const float* Wq = (const float*)d_in[4];
  const float* Wk = (const float*)d_in[5];
  const float* Wv = (const float*)d_in[6];
  const float* Wo = (const float*)d_in[7];

  float* out = (float*)d_out;
  float* wout = out + (size_t)Bb * Ss * HID;  // w output region (fp32)

  char* wsp = (char*)d_ws;
  auto alloc = [&](size_t bytes) {
    char* p = wsp;
    wsp += (bytes + 255) & ~(size_t)255;
    return p;
  };
  float* k     = (float*)alloc((size_t)Bb * NKV * Ss * HD * 4);  // 8.4 MB
  float* vT    = (float*)alloc((size_t)Bb * NKV * Ss * HD * 4);  // 8.4 MB
  float* kmean = (float*)alloc((size_t)Bb * NKV * HD * 4);
  u16* hsb = (u16*)alloc((size_t)Bb * Ss * HID * 2);
  u16* qb  = (u16*)alloc((size_t)Bb * NH * Ss * HD * 2);
  u16* kb  = (u16*)alloc((size_t)Bb * NKV * Ss * HD * 2);
  u16* vTb = (u16*)alloc((size_t)Bb * NKV * Ss * HD * 2);
  u16* Wqb = (u16*)alloc((size_t)NH * HD * HID * 2);
  u16* Wkb = (u16*)alloc((size_t)NKV * HD * HID * 2);
  u16* Wvb = (u16*)alloc((size_t)NKV * HD * HID * 2);
  u16* Wob = (u16*)alloc((size_t)HID * NH * HD * 2);
  u16* attnb = (u16*)alloc((size_t)Bb * Ss * HID * 2);           // 16.8 MB

  // fp32 -> bf16 conversions (single dispatch)
  convert_all<<<CB_HS + CB_WQ + CB_WK + CB_WV + CB_WO, 256, 0, stream>>>(
      hs, Wq, Wk, Wv, Wo, hsb, Wqb, Wkb, Wvb, Wob);

  // fused Q/K/V projection + RoPE + quant(q): qb bf16, k fp32 (roped), vT fp32
  mfma_gemm<M_QKV, HID><<<dim3(24, 16), 256, 0, stream>>>(
      hsb, Wqb, Wkb, Wvb, qb, k, vT, nullptr, cosp, sinp);

  // V quant (independent of k-path)
  vquant<<<Bb * NKV * HD, 256, 0, stream>>>(vT, vTb);
  kmean_kernel<<<Bb * NKV, 1024, 0, stream>>>(k, kmean);
  k_subquant<<<(Bb * NKV * Ss) / 4, 256, 0, stream>>>(k, kb, kmean);

  // fused scores+softmax+quant(w)+PV (1024 blocks, heavy first, pipelined)
  fused_attn<<<dim3(1024), 256, 0, stream>>>(qb, kb, vTb, wout, attnb);

  // out = attn @ Wo^T (128x256 tiles, 16 x 16 blocks)
  mfma_gemm<M_OUT, HID><<<dim3(16, 16), 256, 0, stream>>>(
      attnb, Wob, nullptr, nullptr, nullptr, nullptr, nullptr, out,
      nullptr, nullptr);
}